// Round 1
// baseline (79.789 us; speedup 1.0000x reference)
//
#include <hip/hip_runtime.h>

#define NBINS 5

__global__ __launch_bounds__(256) void ToneMapping_kernel(
    const float* __restrict__ x,
    const float* __restrict__ widths,
    const float* __restrict__ heights,
    const float* __restrict__ slopes,
    float* __restrict__ out,
    long long n4, long long n)
{
    // Per-bin spline parameters, staged in LDS (runtime-indexed lookups are
    // conflict-free: each array spans 5 consecutive words -> distinct banks;
    // same-address lanes broadcast).
    __shared__ float s_edge[NBINS - 1]; // only first 4 edges needed (see below)
    __shared__ float s_xl[NBINS];       // x_low
    __shared__ float s_iw[NBINS];       // 1 / (x_high - x_low + 1e-8)
    __shared__ float s_yl[NBINS];       // y_low
    __shared__ float s_dy[NBINS];       // y_high - y_low
    __shared__ float s_slm2[NBINS];     // slope_low - 2
    __shared__ float s_s[NBINS];        // slope_low + slope_high
    __shared__ float s_s2m4[NBINS];     // 2*(s - 2)

    if (threadIdx.x == 0) {
        // Sequential f32 cumsum, same order as jnp.cumsum -> identical rounding.
        float edges[NBINS], wc[NBINS];
        float c = 0.0f;
        for (int i = 0; i < NBINS; ++i) {
            wc[i] = c;              // widths_cumsum = [0, edges[0..3]]
            c = c + widths[i];
            edges[i] = c;
        }
        for (int i = 0; i < NBINS; ++i) {
            float xl = wc[i];
            float xh = wc[i] + widths[i];   // matches (widths_cumsum + widths)[i]
            s_xl[i] = xl;
            s_iw[i] = 1.0f / (xh - xl + 1e-8f); // full-precision div, once per block
            float yl = heights[i], yh = heights[i + 1];
            s_yl[i] = yl;
            s_dy[i] = yh - yl;
            float sl = slopes[i], sh = slopes[i + 1];
            s_slm2[i] = sl - 2.0f;
            float ss = sl + sh;
            s_s[i]    = ss;
            s_s2m4[i] = 2.0f * (ss - 2.0f);
            if (i < NBINS - 1) s_edge[i] = edges[i];
        }
    }
    __syncthreads();

    long long tid    = (long long)blockIdx.x * blockDim.x + threadIdx.x;
    long long stride = (long long)gridDim.x * blockDim.x;

    const float4* __restrict__ x4 = (const float4*)x;
    float4* __restrict__ o4 = (float4*)out;

    for (long long i = tid; i < n4; i += stride) {
        float4 v = x4[i];
        float in[4]  = {v.x, v.y, v.z, v.w};
        float res[4];
        #pragma unroll
        for (int k = 0; k < 4; ++k) {
            float xf = fminf(fmaxf(in[k], 0.0f), 1.0f);
            // searchsorted(edges, xf, 'left') clipped to NBINS-1:
            // = count of edges[j] < xf over j in [0,4). (edge[4]~1.0 never needed:
            // counting 4 edges == count-all-then-clip since xf<=1.)
            int idx = 0;
            #pragma unroll
            for (int j = 0; j < NBINS - 1; ++j)
                idx += (s_edge[j] < xf) ? 1 : 0;

            float t  = (xf - s_xl[idx]) * s_iw[idx];
            float t2 = t * t;
            // numerator = sl*t^2 + 2t(1-t) = t^2*(sl-2) + 2t
            float num = fmaf(t2, s_slm2[idx], 2.0f * t);
            // denominator = s*t^2 + 2(s-2)*t + 2
            float den = fmaf(s_s[idx], t2, fmaf(s_s2m4[idx], t, 2.0f));
            float r   = __builtin_amdgcn_rcpf(den); // v_rcp_f32, ~1ulp << 1.7e-2 tol
            res[k] = fmaf(s_dy[idx], num * r, s_yl[idx]);
        }
        o4[i] = make_float4(res[0], res[1], res[2], res[3]);
    }

    // Scalar tail (n not divisible by 4) — not hit for this shape, kept for safety.
    long long tail_start = n4 * 4;
    for (long long i = tail_start + tid; i < n; i += stride) {
        float xf = fminf(fmaxf(x[i], 0.0f), 1.0f);
        int idx = 0;
        for (int j = 0; j < NBINS - 1; ++j) idx += (s_edge[j] < xf) ? 1 : 0;
        float t  = (xf - s_xl[idx]) * s_iw[idx];
        float t2 = t * t;
        float num = fmaf(t2, s_slm2[idx], 2.0f * t);
        float den = fmaf(s_s[idx], t2, fmaf(s_s2m4[idx], t, 2.0f));
        out[i] = fmaf(s_dy[idx], num * __builtin_amdgcn_rcpf(den), s_yl[idx]);
    }
}

extern "C" void kernel_launch(void* const* d_in, const int* in_sizes, int n_in,
                              void* d_out, int out_size, void* d_ws, size_t ws_size,
                              hipStream_t stream) {
    const float* x       = (const float*)d_in[0];
    const float* widths  = (const float*)d_in[1];
    const float* heights = (const float*)d_in[2];
    const float* slopes  = (const float*)d_in[3];
    float* out = (float*)d_out;

    long long n  = (long long)in_sizes[0];
    long long n4 = n / 4;

    const int block = 256;
    long long want = (n4 + block - 1) / block;
    int grid = (int)(want < 2048 ? (want > 0 ? want : 1) : 2048); // 8 blocks/CU cap, grid-stride

    ToneMapping_kernel<<<grid, block, 0, stream>>>(x, widths, heights, slopes, out, n4, n);
}